// Round 3
// baseline (164.846 us; speedup 1.0000x reference)
//
#include <hip/hip_runtime.h>
#include <stdint.h>

typedef __attribute__((ext_vector_type(8))) _Float16 half8;
typedef __attribute__((ext_vector_type(2))) _Float16 h2;
typedef __attribute__((ext_vector_type(4))) float f32x4;

#define NCHUNK 32     // 4096 t / 128 t per chunk (2 i-slices per chunk)

static __device__ __forceinline__ unsigned short f2h(float f) {
  return __builtin_bit_cast(unsigned short, (_Float16)f);
}
static __device__ __forceinline__ float h2f_(unsigned short s) {
  return (float)__builtin_bit_cast(_Float16, s);
}
// async global->LDS, 16 B per lane; lds dest must be wave-uniform base
static __device__ __forceinline__ void gload16(const void* g, void* l) {
  __builtin_amdgcn_global_load_lds((const __attribute__((address_space(1))) void*)g,
                                   (__attribute__((address_space(3))) void*)l, 16, 0, 0);
}

// ---- phase 1: M~[k][t] = sum_w wgt[w]*mix[w][k][t] -> f16, 4-way w-split ----
__global__ __launch_bounds__(256) void prep_kernel(const float* __restrict__ mix,
                                                   const float* __restrict__ wgt,
                                                   unsigned short* __restrict__ Bp) {
  __shared__ float4 red[256];
  const int tid = threadIdx.x;
  const int ws  = tid >> 6;
  const int tt  = tid & 63;
  const int t4  = blockIdx.x * 64 + tt;
  const float4* m4 = (const float4*)mix;
  float ax = 0.f, ay = 0.f, az = 0.f, aw = 0.f;
#pragma unroll
  for (int wi = 0; wi < 8; ++wi) {
    const int w = ws * 8 + wi;
    const float s = wgt[w];
    const float4 v = m4[w * 65536 + t4];
    ax += s * v.x; ay += s * v.y; az += s * v.z; aw += s * v.w;
  }
  red[tid] = (float4){ax, ay, az, aw};
  __syncthreads();
  if (tid < 64) {
    const float4 a = red[tid], b = red[tid + 64], c = red[tid + 128], d = red[tid + 192];
    ushort4 r;
    r.x = f2h(a.x + b.x + c.x + d.x);
    r.y = f2h(a.y + b.y + c.y + d.y);
    r.z = f2h(a.z + b.z + c.z + d.z);
    r.w = f2h(a.w + b.w + c.w + d.w);
    ((ushort4*)Bp)[blockIdx.x * 64 + tid] = r;
  }
}

// ---- phase 1b: in-place symmetrize per k-slice (f16).
// Bs[k,i,j] = M~[k,i,j]+M~[k,j,i] (i<j), M~[k,i,i] (diag), 0 (i>j).
__global__ __launch_bounds__(256) void symm_kernel(unsigned short* __restrict__ Bp) {
  unsigned short* B = Bp + (size_t)blockIdx.x * 4096;  // one k per block
  for (int t = threadIdx.x; t < 4096; t += 256) {
    const int i = t >> 6, j = t & 63;
    if (i < j) {
      const int tt = (j << 6) | i;
      const float a = h2f_(B[t]);
      const float b = h2f_(B[tt]);
      B[t]  = f2h(a + b);
      B[tt] = 0;
    }
  }
}

// ---- phase 2: out[z][k] = sum_t V[z,t]*Bs[k,t], V generated in-register ----
// 512 threads (8 waves) = 4 z-groups (wz) x 2 k-halves (wk); block = 128 z.
// Wave tile: 32 z x 32 k  ->  per-chunk LDS B reads halved vs 64k waves,
// one B stage serves 8 waves. f16 pipeline: v_pk_mul_f16 builds packed A
// directly (no pack step). Same XOR-16B-unit swizzle (read bank-conflict-free,
// verified SQ_LDS_BANK_CONFLICT=0) and upper-triangular chunk skip.
__global__ __launch_bounds__(512, 4) void gemm_kernel(const float* __restrict__ X,
                                                      const unsigned short* __restrict__ Bp,
                                                      float* __restrict__ out) {
  __shared__ unsigned short ldsB[2][64 * 128];    // [buf][k][128-t chunk]  32 KB
  __shared__ unsigned short sH[2][2][128];        // [buf][il][dword*2+half] 1 KB

  const int tid  = threadIdx.x;
  const int lane = tid & 63;
  const int wv   = tid >> 6;    // wave 0..7
  const int wz   = wv >> 1;     // z-group 0..3 -> z rows wz*32..+31
  const int wk   = wv & 1;      // k-half 0/1 -> k cols wk*32..+31
  const int m    = lane & 15;
  const int q    = lane >> 4;
  const int zblk = blockIdx.x * 128;

  // stage chunk ct into ldsB[bf]: 8 waves x 2 iters x 1 KB segments.
  // segment s = wv*2+it covers rows 4s..4s+3; lane writes 16 B at dest+lane*16
  // (row = 4s + lane/16, slot u' = lane&15); source unit u = u' ^ (row&15).
  auto stageB = [&](int ct, int bf) {
#pragma unroll
    for (int it = 0; it < 2; ++it) {
      const int seg = wv * 2 + it;
      const int row = seg * 4 + (lane >> 4);
      const int u   = (lane & 15) ^ (row & 15);
      gload16(Bp + (size_t)row * 4096 + ct * 128 + u * 8,
              &ldsB[bf][seg * 512]);
    }
  };

  // ---- prologue: B chunk 0 + s chunk 0 ----
  stageB(0, 0);
  if (tid < 128) {
    const float2 xp = *(const float2*)(X + (size_t)(zblk + tid) * 64);
    const int d  = (tid >> 5) * 16 + (tid & 15);
    const int hf = (tid >> 4) & 1;
    sH[0][0][d * 2 + hf] = f2h(xp.x);
    sH[0][1][d * 2 + hf] = f2h(xp.y);
  }

  // ---- per-lane f16 j-cache: jh[f][h*4+e] = {x[z(f,m), h*32+q*8+2e], x[..,+1]} ----
  h2 jh[2][8];
  {
    const float4* X4g = (const float4*)X;
#pragma unroll
    for (int f = 0; f < 2; ++f) {
      const int zg = zblk + wz * 32 + f * 16 + m;
#pragma unroll
      for (int h = 0; h < 2; ++h) {
        const float4 a = X4g[zg * 16 + h * 8 + q * 2];
        const float4 b = X4g[zg * 16 + h * 8 + q * 2 + 1];
        jh[f][h * 4 + 0] = h2{(_Float16)a.x, (_Float16)a.y};
        jh[f][h * 4 + 1] = h2{(_Float16)a.z, (_Float16)a.w};
        jh[f][h * 4 + 2] = h2{(_Float16)b.x, (_Float16)b.y};
        jh[f][h * 4 + 3] = h2{(_Float16)b.z, (_Float16)b.w};
      }
    }
  }

  f32x4 acc[2][2];
#pragma unroll
  for (int f = 0; f < 2; ++f)
#pragma unroll
    for (int g = 0; g < 2; ++g) acc[f][g] = f32x4{0.f, 0.f, 0.f, 0.f};

  __syncthreads();

  auto chunk_body = [&](int c, bool full) {
    const int cn = (c + 1) & (NCHUNK - 1);
    // async-stage next B chunk (in flight across the MFMA block, drained at barrier)
    stageB(cn, (c + 1) & 1);
    // prefetch next chunk's broadcast x[z, 2cn..2cn+1]
    float2 spre = {0.f, 0.f};
    if (tid < 128)
      spre = *(const float2*)(X + (size_t)(zblk + tid) * 64 + cn * 2);

    const unsigned short* Bl = &ldsB[c & 1][0];
#pragma unroll
    for (int il = 0; il < 2; ++il) {
      const unsigned sv = *(const unsigned*)(&sH[c & 1][il][(wz * 16 + m) * 2]);
      h2 s2f[2];
      s2f[0] = __builtin_bit_cast(h2, __builtin_amdgcn_perm(sv, sv, 0x01000100u)); // {lo,lo}
      s2f[1] = __builtin_bit_cast(h2, __builtin_amdgcn_perm(sv, sv, 0x03020302u)); // {hi,hi}
      auto hblk = [&](int h) {
        const int u = ((il << 3) + (h << 2) + q) ^ m;   // swizzled 16B unit
        const unsigned short* bb = Bl + (wk * 32 + m) * 128 + u * 8;
        const half8 b0 = *(const half8*)(const void*)(bb);            // k = wk*32+m
        const half8 b1 = *(const half8*)(const void*)(bb + 16 * 128); // k = wk*32+16+m
#pragma unroll
        for (int f = 0; f < 2; ++f) {
          union { unsigned u[4]; half8 v; } A;
#pragma unroll
          for (int e = 0; e < 4; ++e) {
            const h2 pr = s2f[f] * jh[f][h * 4 + e];   // v_pk_mul_f16 -> packed A
            A.u[e] = __builtin_bit_cast(unsigned, pr);
          }
          acc[f][0] = __builtin_amdgcn_mfma_f32_16x16x32_f16(A.v, b0, acc[f][0], 0, 0, 0);
          acc[f][1] = __builtin_amdgcn_mfma_f32_16x16x32_f16(A.v, b1, acc[f][1], 0, 0, 0);
        }
      };
      if (full) hblk(0);  // j<32 half: only needed while i<32 (Bs upper-triangular)
      hblk(1);
    }

    // publish next chunk's s-broadcast
    if (tid < 128) {
      const int d  = (tid >> 5) * 16 + (tid & 15);
      const int hf = (tid >> 4) & 1;
      sH[(c + 1) & 1][0][d * 2 + hf] = f2h(spre.x);
      sH[(c + 1) & 1][1][d * 2 + hf] = f2h(spre.y);
    }
    __syncthreads();   // drains vmcnt -> staged B chunk visible
  };

  for (int c = 0; c < 16; ++c)      chunk_body(c, true);   // i < 32: full
  for (int c = 16; c < NCHUNK; ++c) chunk_body(c, false);  // i >= 32: h=1 only

  // ---- epilogue: C/D layout col=lane&15 (k), row=q*4+r (z) ----
#pragma unroll
  for (int f = 0; f < 2; ++f) {
    const int zr = zblk + wz * 32 + f * 16 + q * 4;
#pragma unroll
    for (int g = 0; g < 2; ++g)
#pragma unroll
      for (int r = 0; r < 4; ++r)
        out[(size_t)(zr + r) * 64 + wk * 32 + g * 16 + m] = acc[f][g][r];
  }
}

extern "C" void kernel_launch(void* const* d_in, const int* in_sizes, int n_in,
                              void* d_out, int out_size, void* d_ws, size_t ws_size,
                              hipStream_t stream) {
  const float* X   = (const float*)d_in[0];   // [131072, 64]
  const float* mix = (const float*)d_in[1];   // [32, 64, 64, 64]
  const float* wgt = (const float*)d_in[2];   // [32]
  float* out = (float*)d_out;                 // [131072, 64]
  unsigned short* Bp = (unsigned short*)d_ws; // 512 KB scratch: Bs f16 [64][4096]

  prep_kernel<<<1024, 256, 0, stream>>>(mix, wgt, Bp);
  symm_kernel<<<64, 256, 0, stream>>>(Bp);
  gemm_kernel<<<1024, 512, 0, stream>>>(X, Bp, out);
}

// Round 4
// 161.088 us; speedup vs baseline: 1.0233x; 1.0233x over previous
//
#include <hip/hip_runtime.h>
#include <stdint.h>

typedef __attribute__((ext_vector_type(8))) _Float16 half8;
typedef __attribute__((ext_vector_type(2))) _Float16 h2;
typedef __attribute__((ext_vector_type(4))) float f32x4;

#define NCHUNK 32     // 4096 t / 128 t per chunk (2 i-slices per chunk)

static __device__ __forceinline__ unsigned short f2h(float f) {
  return __builtin_bit_cast(unsigned short, (_Float16)f);
}
static __device__ __forceinline__ float h2f_(unsigned short s) {
  return (float)__builtin_bit_cast(_Float16, s);
}
// async global->LDS, 16 B per lane; lds dest must be wave-uniform base
static __device__ __forceinline__ void gload16(const void* g, void* l) {
  __builtin_amdgcn_global_load_lds((const __attribute__((address_space(1))) void*)g,
                                   (__attribute__((address_space(3))) void*)l, 16, 0, 0);
}

// ---- phase 1: M~[k][t] = sum_w wgt[w]*mix[w][k][t] -> f16, 4-way w-split ----
__global__ __launch_bounds__(256) void prep_kernel(const float* __restrict__ mix,
                                                   const float* __restrict__ wgt,
                                                   unsigned short* __restrict__ Bp) {
  __shared__ float4 red[256];
  const int tid = threadIdx.x;
  const int ws  = tid >> 6;
  const int tt  = tid & 63;
  const int t4  = blockIdx.x * 64 + tt;
  const float4* m4 = (const float4*)mix;
  float ax = 0.f, ay = 0.f, az = 0.f, aw = 0.f;
#pragma unroll
  for (int wi = 0; wi < 8; ++wi) {
    const int w = ws * 8 + wi;
    const float s = wgt[w];
    const float4 v = m4[w * 65536 + t4];
    ax += s * v.x; ay += s * v.y; az += s * v.z; aw += s * v.w;
  }
  red[tid] = (float4){ax, ay, az, aw};
  __syncthreads();
  if (tid < 64) {
    const float4 a = red[tid], b = red[tid + 64], c = red[tid + 128], d = red[tid + 192];
    ushort4 r;
    r.x = f2h(a.x + b.x + c.x + d.x);
    r.y = f2h(a.y + b.y + c.y + d.y);
    r.z = f2h(a.z + b.z + c.z + d.z);
    r.w = f2h(a.w + b.w + c.w + d.w);
    ((ushort4*)Bp)[blockIdx.x * 64 + tid] = r;
  }
}

// ---- phase 1b: in-place symmetrize per k-slice (f16).
// Bs[k,i,j] = M~[k,i,j]+M~[k,j,i] (i<j), M~[k,i,i] (diag), 0 (i>j).
__global__ __launch_bounds__(256) void symm_kernel(unsigned short* __restrict__ Bp) {
  unsigned short* B = Bp + (size_t)blockIdx.x * 4096;  // one k per block
  for (int t = threadIdx.x; t < 4096; t += 256) {
    const int i = t >> 6, j = t & 63;
    if (i < j) {
      const int tt = (j << 6) | i;
      const float a = h2f_(B[t]);
      const float b = h2f_(B[tt]);
      B[t]  = f2h(a + b);
      B[tt] = 0;
    }
  }
}

// ---- phase 2: out[z][k] = sum_t V[z,t]*Bs[k,t], V generated in-register ----
// 512 threads (8 waves) = 4 z-groups (wz) x 2 k-halves (wk); block = 256 z.
// Wave tile: 64 z x 32 k (f=4 A-frags reuse each B read -> 4 MFMA : 1 b128).
// Depth-2 stage pipeline: 3 LDS B buffers; stage chunk c+2 while computing c;
// counted s_waitcnt vmcnt(2) + raw s_barrier keeps the newest stage in flight
// ACROSS the barrier (no vmcnt(0) drain). XOR-16B-unit swizzle as before
// (verified 0 bank conflicts). Upper-triangular Bs: c>=16 skip h=0 half.
__global__ __launch_bounds__(512, 4) void gemm_kernel(const float* __restrict__ X,
                                                      const unsigned short* __restrict__ Bp,
                                                      float* __restrict__ out) {
  __shared__ unsigned short ldsB[3][64 * 128];    // 3 x 16 KB = 48 KB
  __shared__ unsigned short sH[2][2][256];        // [buf][il][dword*2+half] 2 KB

  const int tid  = threadIdx.x;
  const int lane = tid & 63;
  const int wv   = tid >> 6;    // wave 0..7
  const int wz   = wv >> 1;     // z-group 0..3 -> z rows wz*64..+63
  const int wk   = wv & 1;      // k-half 0/1 -> k cols wk*32..+31
  const int m    = lane & 15;
  const int q    = lane >> 4;
  const int zblk = blockIdx.x * 256;

  // stage chunk ct into ldsB[bf]: 8 waves x 2 iters x 1 KB segments.
  // segment s = wv*2+it covers rows 4s..4s+3; lane writes 16 B at dest+lane*16
  // (row = 4s + lane/16, slot u' = lane&15); source unit u = u' ^ (row&15).
  auto stageB = [&](int ct, int bf) {
#pragma unroll
    for (int it = 0; it < 2; ++it) {
      const int seg = wv * 2 + it;
      const int row = seg * 4 + (lane >> 4);
      const int u   = (lane & 15) ^ (row & 15);
      gload16(Bp + (size_t)row * 4096 + ct * 128 + u * 8,
              &ldsB[bf][seg * 512]);
    }
  };

  // s-broadcast publish: dword d = wz*32+m*2+fd holds lo = x[wz*64+fd*32+m, i],
  // hi = x[wz*64+fd*32+16+m, i]. Writer tid (0..255): z_local = tid,
  // bits: wz=tid[7:6], fd=tid[5], hf=tid[4], m=tid[3:0].
  auto publishS = [&](int bf, float2 xp) {
    if (tid < 256) {
      const int d  = (tid >> 6) * 32 + (tid & 15) * 2 + ((tid >> 5) & 1);
      const int hf = (tid >> 4) & 1;
      sH[bf][0][d * 2 + hf] = f2h(xp.x);
      sH[bf][1][d * 2 + hf] = f2h(xp.y);
    }
  };

  // ---- prologue: B chunks 0,1 + s chunk 0 ----
  stageB(0, 0);
  stageB(1, 1);
  {
    float2 xp0 = {0.f, 0.f};
    if (tid < 256) xp0 = *(const float2*)(X + (size_t)(zblk + tid) * 64);
    publishS(0, xp0);
  }

  // ---- per-lane f16 j-cache: jh[f][h*4+e] = {x[z(f,m), h*32+q*8+2e], x[..,+1]} ----
  h2 jh[4][8];
  {
    const float4* X4g = (const float4*)X;
#pragma unroll
    for (int f = 0; f < 4; ++f) {
      const int zg = zblk + wz * 64 + f * 16 + m;
#pragma unroll
      for (int h = 0; h < 2; ++h) {
        const float4 a = X4g[zg * 16 + h * 8 + q * 2];
        const float4 b = X4g[zg * 16 + h * 8 + q * 2 + 1];
        jh[f][h * 4 + 0] = h2{(_Float16)a.x, (_Float16)a.y};
        jh[f][h * 4 + 1] = h2{(_Float16)a.z, (_Float16)a.w};
        jh[f][h * 4 + 2] = h2{(_Float16)b.x, (_Float16)b.y};
        jh[f][h * 4 + 3] = h2{(_Float16)b.z, (_Float16)b.w};
      }
    }
  }

  f32x4 acc[4][2];
#pragma unroll
  for (int f = 0; f < 4; ++f)
#pragma unroll
    for (int g = 0; g < 2; ++g) acc[f][g] = f32x4{0.f, 0.f, 0.f, 0.f};

  __syncthreads();   // one-time full drain: chunks 0,1 staged, sH[0] ready

  int bufc = 0;
  for (int c = 0; c < NCHUNK; ++c) {
    const int cn = (c + 1) & (NCHUNK - 1);
    // issue next s-broadcast load FIRST (older than stage gloads -> the
    // compiler's wait at publishS leaves the 2 newest gloads in flight)
    float2 spre = {0.f, 0.f};
    if (tid < 256)
      spre = *(const float2*)(X + (size_t)(zblk + tid) * 64 + cn * 2);
    // async-stage chunk c+2 into the third buffer (in flight across barrier)
    int bs = bufc + 2; if (bs >= 3) bs -= 3;
    stageB((c + 2) & (NCHUNK - 1), bs);

    const unsigned short* Bl = &ldsB[bufc][0];
    const bool full = (c < 16);
#pragma unroll
    for (int il = 0; il < 2; ++il) {
      // 4 s-values (f=0..3) in one 8 B LDS read
      const uint2 sv = *(const uint2*)(&sH[c & 1][il][wz * 64 + m * 4]);
      h2 s2f[4];
      s2f[0] = __builtin_bit_cast(h2, __builtin_amdgcn_perm(sv.x, sv.x, 0x01000100u));
      s2f[1] = __builtin_bit_cast(h2, __builtin_amdgcn_perm(sv.x, sv.x, 0x03020302u));
      s2f[2] = __builtin_bit_cast(h2, __builtin_amdgcn_perm(sv.y, sv.y, 0x01000100u));
      s2f[3] = __builtin_bit_cast(h2, __builtin_amdgcn_perm(sv.y, sv.y, 0x03020302u));
      auto hblk = [&](int h) {
        const int u = ((il << 3) + (h << 2) + q) ^ m;   // swizzled 16B unit
        const unsigned short* bb = Bl + (wk * 32 + m) * 128 + u * 8;
        const half8 b0 = *(const half8*)(const void*)(bb);            // k = wk*32+m
        const half8 b1 = *(const half8*)(const void*)(bb + 16 * 128); // k = wk*32+16+m
#pragma unroll
        for (int f = 0; f < 4; ++f) {
          union { unsigned u[4]; half8 v; } A;
#pragma unroll
          for (int e = 0; e < 4; ++e) {
            const h2 pr = s2f[f] * jh[f][h * 4 + e];   // v_pk_mul_f16 -> packed A
            A.u[e] = __builtin_bit_cast(unsigned, pr);
          }
          acc[f][0] = __builtin_amdgcn_mfma_f32_16x16x32_f16(A.v, b0, acc[f][0], 0, 0, 0);
          acc[f][1] = __builtin_amdgcn_mfma_f32_16x16x32_f16(A.v, b1, acc[f][1], 0, 0, 0);
        }
      };
      if (full) hblk(0);  // j<32 half: only needed while i<32 (Bs upper-triangular)
      hblk(1);
    }

    publishS(cn & 1, spre);
    // counted wait: chunk c+1's stage (2 oldest gloads) must be done; the 2
    // newest (chunk c+2) stay in flight across the barrier. Explicit asm is
    // required for waves 4..7, which have no register use of their gloads.
    asm volatile("s_waitcnt vmcnt(2)" ::: "memory");
    asm volatile("s_waitcnt lgkmcnt(0)" ::: "memory");
    __builtin_amdgcn_s_barrier();
    __builtin_amdgcn_sched_barrier(0);
    bufc = (bufc + 1 == 3) ? 0 : bufc + 1;
  }

  // ---- epilogue: C/D layout col=lane&15 (k), row=q*4+r (z) ----
#pragma unroll
  for (int f = 0; f < 4; ++f) {
    const int zr = zblk + wz * 64 + f * 16 + q * 4;
#pragma unroll
    for (int g = 0; g < 2; ++g)
#pragma unroll
      for (int r = 0; r < 4; ++r)
        out[(size_t)(zr + r) * 64 + wk * 32 + g * 16 + m] = acc[f][g][r];
  }
}

extern "C" void kernel_launch(void* const* d_in, const int* in_sizes, int n_in,
                              void* d_out, int out_size, void* d_ws, size_t ws_size,
                              hipStream_t stream) {
  const float* X   = (const float*)d_in[0];   // [131072, 64]
  const float* mix = (const float*)d_in[1];   // [32, 64, 64, 64]
  const float* wgt = (const float*)d_in[2];   // [32]
  float* out = (float*)d_out;                 // [131072, 64]
  unsigned short* Bp = (unsigned short*)d_ws; // 512 KB scratch: Bs f16 [64][4096]

  prep_kernel<<<1024, 256, 0, stream>>>(mix, wgt, Bp);
  symm_kernel<<<64, 256, 0, stream>>>(Bp);
  gemm_kernel<<<512, 512, 0, stream>>>(X, Bp, out);
}